// Round 2
// baseline (494.433 us; speedup 1.0000x reference)
//
#include <hip/hip_runtime.h>

// CombineEmbeddings: out[b,s,:] = (idx[b,s] >= 0) ? patch[b, idx[b,s], :]
//                                                 : word[b, s, :]
// B=4, S=4096, P=2048, H=4096, fp32. Pure row-select copy — HBM-bound.
//
// v2b: one 256-thread block per output row (grid = B*S = 16384).
//   - row = blockIdx.x → idx[row] is provably uniform → scalar load +
//     scalar branch (kills the per-lane idx VMEM load the old kernel had).
//   - 4 independent 16B loads per thread (64 B/thread, stride-256 so each
//     instruction is a fully-coalesced 1 KiB wave access) → 4x memory-level
//     parallelism per lane instead of 1.
//   - nontemporal stores: output is write-once, keep it out of L2's way.
//   - native ext_vector_type(4) float (not HIP_vector_type) so
//     __builtin_nontemporal_store accepts the pointer.

#define BB 4
#define SS 4096
#define PP 2048
#define HH 4096

typedef float f4 __attribute__((ext_vector_type(4)));

__global__ __launch_bounds__(256) void CombineEmbeddings_50319836840460_kernel(
    const f4* __restrict__ word,    // [B, S, H/4]
    const f4* __restrict__ patch,   // [B, P, H/4]
    const int* __restrict__ idx,    // [B, S]
    f4*       __restrict__ out)     // [B, S, H/4]
{
    constexpr int Hv = HH / 4;          // 1024 f4 per row

    const int row = blockIdx.x;         // b*S + s   (uniform across block)
    const int b   = row >> 12;          // S = 4096 = 2^12
    const int id  = idx[row];           // uniform → scalar load + scalar branch

    const f4* __restrict__ src = (id >= 0)
        ? patch + (b * PP + id) * Hv    // patch row (coalesced, sequential)
        : word  + row * Hv;             // word row  (identical layout to out)
    f4* __restrict__ dst = out + row * Hv;

    const int c = threadIdx.x;          // 0..255

    // Issue all four loads before any store: 4 outstanding dwordx4 per lane.
    f4 v0 = src[c];
    f4 v1 = src[c + 256];
    f4 v2 = src[c + 512];
    f4 v3 = src[c + 768];

    __builtin_nontemporal_store(v0, &dst[c]);
    __builtin_nontemporal_store(v1, &dst[c + 256]);
    __builtin_nontemporal_store(v2, &dst[c + 512]);
    __builtin_nontemporal_store(v3, &dst[c + 768]);
}

extern "C" void kernel_launch(void* const* d_in, const int* in_sizes, int n_in,
                              void* d_out, int out_size, void* d_ws, size_t ws_size,
                              hipStream_t stream) {
    const f4* word  = (const f4*)d_in[0];
    const f4* patch = (const f4*)d_in[1];
    const int* idx  = (const int*)d_in[2];
    f4*       out   = (f4*)d_out;

    const int grid  = BB * SS;          // 16384 blocks, one per row
    const int block = 256;

    CombineEmbeddings_50319836840460_kernel<<<grid, block, 0, stream>>>(
        word, patch, idx, out);
}

// Round 3
// 484.103 us; speedup vs baseline: 1.0213x; 1.0213x over previous
//
#include <hip/hip_runtime.h>

// CombineEmbeddings: out[b,s,:] = (idx[b,s] >= 0) ? patch[b, idx[b,s], :]
//                                                 : word[b, s, :]
// B=4, S=4096, P=2048, H=4096, fp32. Pure row-select copy — HBM-bound.
//
// v3: two rows per 256-thread block (grid = B*S/2 = 8192).
//   - rows 2*bid, 2*bid+1 → idx[] reads are provably uniform AND adjacent:
//     compiler emits one s_load_dwordx2 + scalar pointer selects (no per-lane
//     idx load, no divergence).
//   - 8 independent 16B loads per lane (128 B in flight) before any store —
//     deep MLP without relying on TLP alone.
//   - NO nontemporal stores: v2's nt regressed ~27 µs (suspected loss of L2
//     write-coalescing). Plain global_store_dwordx4 like the 467 µs baseline.
//   - rows of a pair never straddle a batch: batch = row>>12, r0 even, so
//     r0 and r0+1 share b.

#define BB 4
#define SS 4096
#define PP 2048
#define HH 4096

typedef float f4 __attribute__((ext_vector_type(4)));

__global__ __launch_bounds__(256) void CombineEmbeddings_50319836840460_kernel(
    const f4* __restrict__ word,    // [B, S, H/4]
    const f4* __restrict__ patch,   // [B, P, H/4]
    const int* __restrict__ idx,    // [B, S]
    f4*       __restrict__ out)     // [B, S, H/4]
{
    constexpr int Hv = HH / 4;          // 1024 f4 per row

    const int r0 = blockIdx.x * 2;      // first of two rows (uniform)
    const int r1 = r0 + 1;
    const int b  = r0 >> 12;            // S = 4096 = 2^12; same batch for r0,r1

    const int id0 = idx[r0];            // adjacent → one s_load_dwordx2
    const int id1 = idx[r1];

    const f4* __restrict__ s0 = (id0 >= 0) ? patch + (b * PP + id0) * Hv
                                           : word  + r0 * Hv;
    const f4* __restrict__ s1 = (id1 >= 0) ? patch + (b * PP + id1) * Hv
                                           : word  + r1 * Hv;
    f4* __restrict__ d0 = out + r0 * Hv;
    f4* __restrict__ d1 = out + r1 * Hv;

    const int c = threadIdx.x;          // 0..255

    // 8 independent dwordx4 loads in flight per lane.
    f4 a0 = s0[c];
    f4 a1 = s0[c + 256];
    f4 a2 = s0[c + 512];
    f4 a3 = s0[c + 768];
    f4 b0 = s1[c];
    f4 b1 = s1[c + 256];
    f4 b2 = s1[c + 512];
    f4 b3 = s1[c + 768];

    d0[c]       = a0;
    d0[c + 256] = a1;
    d0[c + 512] = a2;
    d0[c + 768] = a3;
    d1[c]       = b0;
    d1[c + 256] = b1;
    d1[c + 512] = b2;
    d1[c + 768] = b3;
}

extern "C" void kernel_launch(void* const* d_in, const int* in_sizes, int n_in,
                              void* d_out, int out_size, void* d_ws, size_t ws_size,
                              hipStream_t stream) {
    const f4* word  = (const f4*)d_in[0];
    const f4* patch = (const f4*)d_in[1];
    const int* idx  = (const int*)d_in[2];
    f4*       out   = (f4*)d_out;

    const int grid  = BB * SS / 2;      // 8192 blocks, two rows per block
    const int block = 256;

    CombineEmbeddings_50319836840460_kernel<<<grid, block, 0, stream>>>(
        word, patch, idx, out);
}

// Round 4
// 476.167 us; speedup vs baseline: 1.0384x; 1.0167x over previous
//
#include <hip/hip_runtime.h>

// CombineEmbeddings: out[b,s,:] = (idx[b,s] >= 0) ? patch[b, idx[b,s], :]
//                                                 : word[b, s, :]
// B=4, S=4096, P=2048, H=4096, fp32. Pure row-select copy — HBM-bound.
//
// v4: minimal step from the 467.6 µs v1 (flat mapping, plain stores).
//   ONE change: each lane handles 2 float4 from the SAME row at stride 512
//   (cols c and c+512). Grid 32768 × 256 (2 blocks/row).
//   - halves idx loads + address setup per byte moved
//   - 2 independent dwordx4 loads in flight per lane (2x MLP vs v1)
//   - coalescing identical to v1: each load/store instruction is a perfect
//     1 KiB wave access; global traversal order near-identical to v1.
//   - NO nontemporal stores (v2: −11 µs regression), NO row-block mapping
//     (v3: −16 µs regression).

#define BB 4
#define SS 4096
#define PP 2048
#define HH 4096

typedef float f4 __attribute__((ext_vector_type(4)));

__global__ __launch_bounds__(256) void CombineEmbeddings_50319836840460_kernel(
    const f4* __restrict__ word,    // [B, S, H/4]
    const f4* __restrict__ patch,   // [B, P, H/4]
    const int* __restrict__ idx,    // [B, S]
    f4*       __restrict__ out)     // [B, S, H/4]
{
    constexpr int Hv = HH / 4;          // 1024 f4 per row
    constexpr int HALF = Hv / 2;        // 512

    const int t   = blockIdx.x * 256 + threadIdx.x;   // < 8,388,608
    const int row = t >> 9;             // b*S + s  (512 threads per row)
    const int c   = t & (HALF - 1);     // 0..511
    const int b   = row >> 12;          // S = 4096 = 2^12

    const int id  = idx[row];           // wave-uniform address (1 L1 request)

    const f4* __restrict__ src = (id >= 0)
        ? patch + (b * PP + id) * Hv
        : word  + row * Hv;
    f4* __restrict__ dst = out + row * Hv;

    // Two independent loads in flight, then two stores. All perfectly
    // coalesced (lane i -> base + 16*i within each instruction).
    f4 v0 = src[c];
    f4 v1 = src[c + HALF];
    dst[c]        = v0;
    dst[c + HALF] = v1;
}

extern "C" void kernel_launch(void* const* d_in, const int* in_sizes, int n_in,
                              void* d_out, int out_size, void* d_ws, size_t ws_size,
                              hipStream_t stream) {
    const f4* word  = (const f4*)d_in[0];
    const f4* patch = (const f4*)d_in[1];
    const int* idx  = (const int*)d_in[2];
    f4*       out   = (f4*)d_out;

    const int grid  = BB * SS * (HH / 4) / 2 / 256;   // 32768 blocks
    const int block = 256;

    CombineEmbeddings_50319836840460_kernel<<<grid, block, 0, stream>>>(
        word, patch, idx, out);
}

// Round 5
// 464.065 us; speedup vs baseline: 1.0654x; 1.0261x over previous
//
#include <hip/hip_runtime.h>

// CombineEmbeddings: out[b,s,:] = (idx[b,s] >= 0) ? patch[b, idx[b,s], :]
//                                                 : word[b, s, :]
// B=4, S=4096, P=2048, H=4096, fp32. Pure row-select copy — HBM-bound.
//
// v5: EXACT v1 structure (1 float4/lane, flat 1:1 mapping, 65536x256 —
//   the best measured: 467.6) with ONE change: data loads are
//   __builtin_nontemporal_load (no-allocate / evict-first in L2/LLC).
//   Mechanism: read streams are read-once — caching them is pure pollution
//   that evicts the 256 MiB write stream (≈ LLC size) and forces full
//   in-kernel writeback. NT loads keep the write stream resident.
//   (v2's regression was NT on STORES — the opposite policy: it evicted
//   the write stream. Loads stay plain for idx, which IS reused.)
//   Experiments v2-v4 showed any extra per-lane work or remapping regresses:
//   keep 1:1 flat, plain stores, per-lane wave-uniform idx load.

#define BB 4
#define SS 4096
#define PP 2048
#define HH 4096

typedef float f4 __attribute__((ext_vector_type(4)));

__global__ __launch_bounds__(256) void CombineEmbeddings_50319836840460_kernel(
    const f4* __restrict__ word,    // [B, S, H/4]
    const f4* __restrict__ patch,   // [B, P, H/4]
    const int* __restrict__ idx,    // [B, S]
    f4*       __restrict__ out)     // [B, S, H/4]
{
    const int Hv = HH / 4;  // 1024 float4 per row
    long long t = (long long)blockIdx.x * blockDim.x + threadIdx.x;
    int row = (int)(t >> 10);          // b*S + s   (Hv = 1024 = 2^10)
    int col = (int)(t & (Hv - 1));
    int b   = row >> 12;               // row / S   (S = 4096 = 2^12)

    int id = idx[row];                 // wave-uniform address (cached, plain)
    f4 v;
    if (id >= 0) {
        v = __builtin_nontemporal_load(
                patch + ((long long)b * PP + id) * Hv + col);
    } else {
        v = __builtin_nontemporal_load(word + t);  // word layout == out layout
    }
    out[t] = v;                        // plain store: let L2/LLC hold it
}

extern "C" void kernel_launch(void* const* d_in, const int* in_sizes, int n_in,
                              void* d_out, int out_size, void* d_ws, size_t ws_size,
                              hipStream_t stream) {
    const f4* word  = (const f4*)d_in[0];
    const f4* patch = (const f4*)d_in[1];
    const int* idx  = (const int*)d_in[2];
    f4*       out   = (f4*)d_out;

    const long long total_vec = (long long)BB * SS * (HH / 4);  // 16,777,216
    const int block = 256;
    const int grid  = (int)(total_vec / block);                 // 65,536

    CombineEmbeddings_50319836840460_kernel<<<grid, block, 0, stream>>>(
        word, patch, idx, out);
}